// Round 2
// baseline (1780.774 us; speedup 1.0000x reference)
//
#include <hip/hip_runtime.h>
#include <stdint.h>

// SIREN batched MLP, MI355X/gfx950 — round 2: register-resident activations.
// Layers: L1 2->128 (MFMA, K-padded, bias as K=2 column), L2/L3 128->128 split
// hi/lo (3-term MFMA), L4 128->128 plain f16, L5 128->3 plain f16 (M-padded).
// One block = (batch, 4096-point slab). Weights: frag-ordered images in LDS
// (144 KB dynamic), L3-lo streamed from global. No barriers in the main loop.

typedef _Float16 f16x8 __attribute__((ext_vector_type(8)));
typedef float f32x16 __attribute__((ext_vector_type(16)));

#define MFMA __builtin_amdgcn_mfma_f32_32x32x16_f16

#define B_ 32
#define N_ 32768

// flat param offsets (floats)
#define OFF_W1 0
#define OFF_B1 256
#define OFF_W2 384
#define OFF_B2 16768
#define OFF_W3 16896
#define OFF_B3 33280
#define OFF_W4 33408
#define OFF_B4 49792
#define OFF_W5 49920
#define OFF_B5 50304
#define NPARAM 50307

// ws per-batch image offsets (bytes); frag-ordered: [c][mt][lane]*16B
#define O_L1H 0
#define O_L1L 4096
#define O_L2H 8192
#define O_W2L 40960
#define O_L3H 73728
#define O_L4H 106496
#define O_L5H 139264
#define LDSSET 147456          /* bytes staged to LDS */
#define O_W3L 147456           /* streamed from global */
#define SWS   180224           /* per-batch ws stride */

__device__ __forceinline__ float fast_sin30(float v) {
    float t = v * 4.77464829275686f;   // 30 / (2*pi)
    t = t - floorf(t);
    return __builtin_amdgcn_sinf(t);
}

__device__ __forceinline__ uint32_t pack2(_Float16 a, _Float16 b) {
    union { _Float16 h[2]; uint32_t u; } x;
    x.h[0] = a; x.h[1] = b;
    return x.u;
}

// ---------------------------------------------------------------------------
// Prep: split params into f16 hi/lo, A-frag-ordered images.
// A-frag for 32x32x16_f16: lane l holds A[m = 32*mt + (l&31)][k = 16c + 8*(l>>5) + e].
// ---------------------------------------------------------------------------
__global__ __launch_bounds__(64) void siren_prep(const float* __restrict__ p0,
                                                 char* __restrict__ ws) {
    const int u = blockIdx.x;      // 0..107 image unit
    const int b = blockIdx.y;
    const int lane = threadIdx.x;
    const int jn = lane & 31;
    const int h = lane >> 5;
    const float* p = p0 + (size_t)b * NPARAM;
    char* wb = ws + (size_t)b * SWS;

    float v[8];
    size_t hoff = 0, loff = 0;
    bool haslo = false;

    if (u < 4) {                               // L1: [mt][lane], k=0:Wx 1:Wy 2:bias
        int mt = u, j = mt * 32 + jn;
#pragma unroll
        for (int e = 0; e < 8; ++e) {
            int k = h * 8 + e;
            v[e] = (k == 0) ? p[OFF_W1 + j * 2]
                 : (k == 1) ? p[OFF_W1 + j * 2 + 1]
                 : (k == 2) ? p[OFF_B1 + j] : 0.f;
        }
        hoff = O_L1H + (size_t)(mt * 64 + lane) * 16;
        loff = O_L1L + (size_t)(mt * 64 + lane) * 16;
        haslo = true;
    } else if (u < 100) {                      // L2/L3/L4: [c][mt][lane]
        int vv = u - 4;
        int layer = vv >> 5;                   // 0,1,2
        int r = vv & 31;
        int c = r >> 2, mt = r & 3;
        int j = mt * 32 + jn, kb = c * 16 + h * 8;
        int wOff = (layer == 0) ? OFF_W2 : (layer == 1) ? OFF_W3 : OFF_W4;
#pragma unroll
        for (int e = 0; e < 8; ++e) v[e] = p[wOff + j * 128 + kb + e];
        size_t idx = (size_t)((c * 4 + mt) * 64 + lane) * 16;
        if (layer == 0)      { hoff = O_L2H + idx; loff = O_W2L + idx; haslo = true; }
        else if (layer == 1) { hoff = O_L3H + idx; loff = O_W3L + idx; haslo = true; }
        else                 { hoff = O_L4H + idx; haslo = false; }
    } else {                                   // L5: [c][lane], rows 3..31 zero
        int c = u - 100, j = jn, kb = c * 16 + h * 8;
#pragma unroll
        for (int e = 0; e < 8; ++e) v[e] = (j < 3) ? p[OFF_W5 + j * 128 + kb + e] : 0.f;
        hoff = O_L5H + (size_t)(c * 64 + lane) * 16;
        haslo = false;
    }

    f16x8 hv, lv;
#pragma unroll
    for (int e = 0; e < 8; ++e) {
        _Float16 hh = (_Float16)v[e];
        hv[e] = hh;
        lv[e] = (_Float16)(v[e] - (float)hh);
    }
    *(f16x8*)(wb + hoff) = hv;
    if (haslo) *(f16x8*)(wb + loff) = lv;
}

// ---------------------------------------------------------------------------
// Main kernel: 512 threads = 8 waves; wave processes 32 points/iter, 16 iters.
// ---------------------------------------------------------------------------
__global__ __launch_bounds__(512, 2) void siren_main(const float* __restrict__ xg,
                                                     const float* __restrict__ pg,
                                                     float* __restrict__ out,
                                                     const char* __restrict__ ws) {
    extern __shared__ __align__(16) char smem[];
    __shared__ float sBias[3][128];

    const int t = threadIdx.x;
    const int b = blockIdx.x;          // batch (x-major -> same batch per XCD group)
    const int grp = blockIdx.y;        // point slab
    const char* wb = ws + (size_t)b * SWS;
    const float* p = pg + (size_t)b * NPARAM;

    // stage weight images to LDS: 147456 B = 9216 float4 = 512 thr * 18
    {
        const float4* src = (const float4*)wb;
        float4* dst = (float4*)smem;
#pragma unroll
        for (int i = 0; i < 18; ++i) dst[t + i * 512] = src[t + i * 512];
    }
    if (t < 384) {
        int li = t >> 7, f = t & 127;
        sBias[li][f] = p[(li == 0 ? OFF_B2 : li == 1 ? OFF_B3 : OFF_B4) + f];
    }
    const float b5_0 = p[OFF_B5], b5_1 = p[OFF_B5 + 1], b5_2 = p[OFF_B5 + 2];
    __syncthreads();

    const int lane = t & 63;
    const int wv = t >> 6;
    const int n = lane & 31;
    const int h = lane >> 5;
    const int lb = lane * 16;

    union UF { f16x8 v; uint32_t w[4]; };

    // acc bias init: feat of reg r = 32mt + (r&3) + 8(r>>2) + 4h
    auto init_bias = [&](f32x16 (&ac)[4], int li) {
#pragma unroll
        for (int mt = 0; mt < 4; ++mt)
#pragma unroll
            for (int rg = 0; rg < 4; ++rg) {
                float4 bb = *(const float4*)&sBias[li][mt * 32 + rg * 8 + h * 4];
                ac[mt][rg * 4 + 0] = bb.x; ac[mt][rg * 4 + 1] = bb.y;
                ac[mt][rg * 4 + 2] = bb.z; ac[mt][rg * 4 + 3] = bb.w;
            }
    };

    // epilogue: sine, split, in-register relayout acc -> next-layer B-frags.
    // chunk c uses tile mt=c>>1 regs g0..g0+7 (g0=(c&1)*8); low-half lanes keep
    // elems 0-3 / send 4-7, high-half lanes keep 4-7 / send 0-3 (via shfl_xor 32).
    auto epi_split = [&](f32x16 (&ac)[4], UF (&Xh)[8], UF (&Xl)[8]) {
#pragma unroll
        for (int c = 0; c < 8; ++c) {
            const int mt = c >> 1, g0 = (c & 1) * 8;
            _Float16 hh[8]; float lo[8];
#pragma unroll
            for (int i = 0; i < 8; ++i) {
                float s = fast_sin30(ac[mt][g0 + i]);
                hh[i] = (_Float16)s;
                lo[i] = s - (float)hh[i];
            }
            uint32_t hw0 = pack2(hh[0], hh[1]), hw1 = pack2(hh[2], hh[3]);
            uint32_t hw2 = pack2(hh[4], hh[5]), hw3 = pack2(hh[6], hh[7]);
            _Float16 ll[8];
#pragma unroll
            for (int i = 0; i < 8; ++i) ll[i] = (_Float16)lo[i];
            uint32_t lw0 = pack2(ll[0], ll[1]), lw1 = pack2(ll[2], ll[3]);
            uint32_t lw2 = pack2(ll[4], ll[5]), lw3 = pack2(ll[6], ll[7]);

            uint32_t rA = (uint32_t)__shfl_xor((int)(h ? hw0 : hw2), 32);
            uint32_t rB = (uint32_t)__shfl_xor((int)(h ? hw1 : hw3), 32);
            Xh[c].w[0] = h ? rA : hw0;  Xh[c].w[1] = h ? rB : hw1;
            Xh[c].w[2] = h ? hw2 : rA;  Xh[c].w[3] = h ? hw3 : rB;

            uint32_t sA = (uint32_t)__shfl_xor((int)(h ? lw0 : lw2), 32);
            uint32_t sB = (uint32_t)__shfl_xor((int)(h ? lw1 : lw3), 32);
            Xl[c].w[0] = h ? sA : lw0;  Xl[c].w[1] = h ? sB : lw1;
            Xl[c].w[2] = h ? lw2 : sA;  Xl[c].w[3] = h ? lw3 : sB;
        }
    };

    auto epi_hi = [&](f32x16 (&ac)[4], UF (&Xh)[8]) {
#pragma unroll
        for (int c = 0; c < 8; ++c) {
            const int mt = c >> 1, g0 = (c & 1) * 8;
            _Float16 hh[8];
#pragma unroll
            for (int i = 0; i < 8; ++i) hh[i] = (_Float16)fast_sin30(ac[mt][g0 + i]);
            uint32_t hw0 = pack2(hh[0], hh[1]), hw1 = pack2(hh[2], hh[3]);
            uint32_t hw2 = pack2(hh[4], hh[5]), hw3 = pack2(hh[6], hh[7]);
            uint32_t rA = (uint32_t)__shfl_xor((int)(h ? hw0 : hw2), 32);
            uint32_t rB = (uint32_t)__shfl_xor((int)(h ? hw1 : hw3), 32);
            Xh[c].w[0] = h ? rA : hw0;  Xh[c].w[1] = h ? rB : hw1;
            Xh[c].w[2] = h ? hw2 : rA;  Xh[c].w[3] = h ? hw3 : rB;
        }
    };

    const f16x8* g3l = (const f16x8*)(wb + O_W3L);

    for (int iter = 0; iter < 16; ++iter) {
        const int pt = grp * 4096 + iter * 256 + wv * 32 + n;
        const float2 xy = ((const float2*)xg)[(size_t)b * N_ + pt];

        f32x16 acc[4];
        UF X1h[8], X1l[8];

        // ---- L1 (split, 1 chunk; bias folded at k=2 with B=1.0)
        {
            UF bh, bl;
            bh.w[0] = bh.w[1] = bh.w[2] = bh.w[3] = 0u;
            bl.w[0] = bl.w[1] = bl.w[2] = bl.w[3] = 0u;
            if (h == 0) {
                _Float16 xh = (_Float16)xy.x, yh = (_Float16)xy.y;
                _Float16 xl = (_Float16)(xy.x - (float)xh);
                _Float16 yl = (_Float16)(xy.y - (float)yh);
                bh.w[0] = pack2(xh, yh);
                bh.w[1] = 0x00003C00u;         // e2 = 1.0h
                bl.w[0] = pack2(xl, yl);
            }
#pragma unroll
            for (int mt = 0; mt < 4; ++mt) {
                f16x8 ah = *(const f16x8*)(smem + O_L1H + mt * 1024 + lb);
                f16x8 al = *(const f16x8*)(smem + O_L1L + mt * 1024 + lb);
                f32x16 a;
#pragma unroll
                for (int i = 0; i < 16; ++i) a[i] = 0.f;
                a = MFMA(ah, bh.v, a, 0, 0, 0);
                a = MFMA(ah, bl.v, a, 0, 0, 0);
                a = MFMA(al, bh.v, a, 0, 0, 0);
                acc[mt] = a;
            }
        }
        epi_split(acc, X1h, X1l);

        // ---- L2 (split): hi + lo from LDS
        init_bias(acc, 0);
#pragma unroll
        for (int c = 0; c < 8; ++c)
#pragma unroll
            for (int mt = 0; mt < 4; ++mt) {
                f16x8 ah = *(const f16x8*)(smem + O_L2H + c * 4096 + mt * 1024 + lb);
                f16x8 al = *(const f16x8*)(smem + O_W2L + c * 4096 + mt * 1024 + lb);
                acc[mt] = MFMA(ah, X1h[c].v, acc[mt], 0, 0, 0);
                acc[mt] = MFMA(ah, X1l[c].v, acc[mt], 0, 0, 0);
                acc[mt] = MFMA(al, X1h[c].v, acc[mt], 0, 0, 0);
            }
        UF X2h[8], X2l[8];
        epi_split(acc, X2h, X2l);

        // ---- L3 (split): hi from LDS, lo streamed from global (double-buffered)
        init_bias(acc, 1);
        {
            f16x8 wl[2][4];
#pragma unroll
            for (int mt = 0; mt < 4; ++mt) wl[0][mt] = g3l[mt * 64 + lane];
#pragma unroll
            for (int c = 0; c < 8; ++c) {
                if (c < 7) {
#pragma unroll
                    for (int mt = 0; mt < 4; ++mt)
                        wl[(c + 1) & 1][mt] = g3l[((c + 1) * 4 + mt) * 64 + lane];
                }
#pragma unroll
                for (int mt = 0; mt < 4; ++mt) {
                    f16x8 ah = *(const f16x8*)(smem + O_L3H + c * 4096 + mt * 1024 + lb);
                    acc[mt] = MFMA(ah, X2h[c].v, acc[mt], 0, 0, 0);
                    acc[mt] = MFMA(ah, X2l[c].v, acc[mt], 0, 0, 0);
                    acc[mt] = MFMA(wl[c & 1][mt], X2h[c].v, acc[mt], 0, 0, 0);
                }
            }
        }
        UF X3h[8];
        epi_hi(acc, X3h);

        // ---- L4 (plain f16)
        init_bias(acc, 2);
#pragma unroll
        for (int c = 0; c < 8; ++c)
#pragma unroll
            for (int mt = 0; mt < 4; ++mt) {
                f16x8 ah = *(const f16x8*)(smem + O_L4H + c * 4096 + mt * 1024 + lb);
                acc[mt] = MFMA(ah, X3h[c].v, acc[mt], 0, 0, 0);
            }
        UF X4h[8];
        epi_hi(acc, X4h);

        // ---- L5 (plain f16, single M-tile, rows 3..31 zero)
        {
            f32x16 a5;
#pragma unroll
            for (int i = 0; i < 16; ++i) a5[i] = 0.f;
#pragma unroll
            for (int c = 0; c < 8; ++c) {
                f16x8 ah = *(const f16x8*)(smem + O_L5H + c * 1024 + lb);
                a5 = MFMA(ah, X4h[c].v, a5, 0, 0, 0);
            }
            if (h == 0) {
                size_t o = ((size_t)b * N_ + pt) * 3;
                struct F3 { float a, b, c; };
                F3 r; r.a = a5[0] + b5_0; r.b = a5[1] + b5_1; r.c = a5[2] + b5_2;
                *(F3*)(out + o) = r;
            }
        }
    }
}

extern "C" void kernel_launch(void* const* d_in, const int* in_sizes, int n_in,
                              void* d_out, int out_size, void* d_ws, size_t ws_size,
                              hipStream_t stream) {
    (void)in_sizes; (void)n_in; (void)out_size; (void)ws_size;
    const float* x = (const float*)d_in[0];
    const float* p = (const float*)d_in[1];
    float* o = (float*)d_out;
    char* ws = (char*)d_ws;   // needs 32 * 180224 = 5,767,168 B

    hipFuncSetAttribute(reinterpret_cast<const void*>(siren_main),
                        hipFuncAttributeMaxDynamicSharedMemorySize, LDSSET);
    siren_prep<<<dim3(108, 32), 64, 0, stream>>>(p, ws);
    siren_main<<<dim3(32, 8), 512, LDSSET, stream>>>(x, p, o, ws);
}